// Round 7
// baseline (201.880 us; speedup 1.0000x reference)
//
#include <hip/hip_runtime.h>

#define L_IN   4000
#define CIN    512
#define KSZ    16
#define LOUT   31992   // 8 * 3999
#define NQ     3999    // valid q: 0..3998
#define NCH    8       // ci chunks per sample
#define CPC    64      // ci per chunk
#define PSTR   32768   // partial stride per (b, chunk), floats
#define PBSTR  (NCH * PSTR)   // per-b partial stride

// ---------------- Phase 1: full-row streaming, partials to ws ---------------
// Block = (chunk c, sample b), 1024 threads. Each iteration the WHOLE block
// consumes one full 16 KB x-row: thread t loads row[4t..4t+3] -> the block's
// address stream over the 64-ci loop is one perfectly sequential 1 MB span
// (rows of a chunk are adjacent in memory). This removes the 16 KB stride
// that capped R2-R6 at ~2.4 TB/s regardless of config.
// Weights are block-uniform per iteration -> scalar (s_load) path, no LDS.
// Thread accumulates its 32 contiguous outputs (q = 4t..4t+3, 8 taps each)
// in registers and writes them contiguously to ws (L2 merges the lane-strided
// float4 pieces into full lines).
__global__ __launch_bounds__(1024, 4)
void dereverb_phase1(const float* __restrict__ x,
                     const float* __restrict__ t60s,
                     const float* __restrict__ kw,
                     float* __restrict__ ws)
{
    const int c = blockIdx.x;
    const int b = blockIdx.y;
    const int t = threadIdx.x;

    // Per-sample kernel index (uniform): jnp.round = RNE = rintf.
    float t60 = t60s[b & 7];
    int kidx = (int)rintf(t60 * 100.0f) - 10;
    kidx = __builtin_amdgcn_readfirstlane(kidx);
    // Fully uniform pointer -> compiler emits s_load for the weight reads.
    const float4* wp = (const float4*)(kw + (size_t)kidx * (CIN * KSZ)
                                          + (size_t)c * (CPC * KSZ));

    // Thread's q-quad: q = 4t + qi. Row has 4000 floats = 1000 float4s;
    // clamp threads >= 1000 onto the last quad (their results are discarded).
    const int q4 = 4 * t;
    const int qa = q4 < 3996 ? q4 : 3996;          // float4-aligned, in-bounds
    int qh = q4 + 4;                                // halo x[q+4] (qi=3 only)
    if (qh > 3999) qh = 3999;                       // clamped: qi=3 invalid then

    const float* xr = x + ((size_t)b * CIN + (size_t)c * CPC) * L_IN;
    const float* xp = xr + qa;
    const float* xq = xr + qh;

    float acc[32];
    #pragma unroll
    for (int j = 0; j < 32; ++j) acc[j] = 0.0f;

    #pragma unroll 2
    for (int ci = 0; ci < CPC; ++ci) {
        float4 a  = *(const float4*)xp;   // block-contiguous 16 KB row read
        float  an = *xq;                  // halo (same row, L1-hit)
        xp += L_IN;
        xq += L_IN;

        float4 w0 = wp[4 * ci + 0];       // uniform -> s_load_dwordx4
        float4 w1 = wp[4 * ci + 1];
        float4 w2 = wp[4 * ci + 2];
        float4 w3 = wp[4 * ci + 3];
        const float wf[16] = {w0.x, w0.y, w0.z, w0.w, w1.x, w1.y, w1.z, w1.w,
                              w2.x, w2.y, w2.z, w2.w, w3.x, w3.y, w3.z, w3.w};

        const float x0v[4] = {a.x, a.y, a.z, a.w};
        const float x1v[4] = {a.y, a.z, a.w, an};
        #pragma unroll
        for (int qi = 0; qi < 4; ++qi)
            #pragma unroll
            for (int r = 0; r < 8; ++r) {
                acc[qi * 8 + r] = fmaf(x1v[qi], wf[r],     acc[qi * 8 + r]);
                acc[qi * 8 + r] = fmaf(x0v[qi], wf[r + 8], acc[qi * 8 + r]);
            }
    }

    // Zero invalid q (> 3998): covers clamped threads and the q=3999 tail.
    #pragma unroll
    for (int qi = 0; qi < 4; ++qi)
        if (q4 + qi > NQ - 1)
            #pragma unroll
            for (int r = 0; r < 8; ++r) acc[qi * 8 + r] = 0.0f;

    // Partial store: 32 contiguous floats at ws[b][c][32t .. 32t+31].
    float* pd = ws + (size_t)b * PBSTR + (size_t)c * PSTR + 32 * t;
    #pragma unroll
    for (int k = 0; k < 8; ++k)
        ((float4*)pd)[k] = ((const float4*)acc)[k];
}

// ---------------- Phase 2: reduce 8 chunk-partials per sample ---------------
__global__ __launch_bounds__(1024)
void dereverb_phase2(const float* __restrict__ ws,
                     float* __restrict__ out)
{
    const int k = blockIdx.x;            // 8 segments of 4096 outputs
    const int b = blockIdx.y;
    const int i = (k << 12) + 4 * threadIdx.x;
    if (i < LOUT) {                      // LOUT % 4 == 0 -> full float4 valid
        const float* p = ws + (size_t)b * PBSTR + i;
        float4 s = make_float4(0.f, 0.f, 0.f, 0.f);
        #pragma unroll
        for (int c = 0; c < NCH; ++c) {
            float4 v = *(const float4*)(p + c * PSTR);
            s.x += v.x; s.y += v.y; s.z += v.z; s.w += v.w;
        }
        *(float4*)(out + (size_t)b * LOUT + i) = s;
    }
}

extern "C" void kernel_launch(void* const* d_in, const int* in_sizes, int n_in,
                              void* d_out, int out_size, void* d_ws, size_t ws_size,
                              hipStream_t stream) {
    const float* x    = (const float*)d_in[0];   // (16, 512, 4000)
    const float* t60s = (const float*)d_in[1];   // (8,)
    const float* kw   = (const float*)d_in[2];   // (41, 512, 1, 16)
    float* out = (float*)d_out;                  // (16, 1, 31992)
    float* ws  = (float*)d_ws;                   // 16 MB partials

    dim3 g1(NCH, 16);                            // 128 blocks
    dereverb_phase1<<<g1, 1024, 0, stream>>>(x, t60s, kw, ws);
    dim3 g2(8, 16);                              // 128 blocks
    dereverb_phase2<<<g2, 1024, 0, stream>>>(ws, out);
}

// Round 8
// 199.499 us; speedup vs baseline: 1.0119x; 1.0119x over previous
//
#include <hip/hip_runtime.h>

#define L_IN   4000
#define CIN    512
#define KSZ    16
#define LOUT   31992   // 8 * 3999
#define NQ     3999    // valid q: 0..3998
#define NCH    8       // ci chunks per sample
#define CPC    64      // ci per chunk
#define QHALF  2000    // q positions per half-block
#define PSTR   32768   // partial stride per (b, chunk), floats
#define PBSTR  (NCH * PSTR)

// ---------------- Phase 1: full-chip sequential streaming -------------------
// Block = (chunk c, q-half h, sample b): 16 b x 8 c x 2 h = 256 blocks
// (1/CU -> whole chip busy; R7's 128-block grid idled half the GPU).
// Block walks its 64 rows reading an 8 KB contiguous run per row (DRAM
// page-friendly, unlike R2-R6's 0.25-1 KB fragments at 16000 B stride).
// Thread t (t < 1000): 2 q's (q = h*2000 + 2t), 8 taps each; weights are
// block-uniform -> scalar s_load path, no LDS. Partials to ws, coalesced.
__global__ __launch_bounds__(1024, 4)
void dereverb_phase1(const float* __restrict__ x,
                     const float* __restrict__ t60s,
                     const float* __restrict__ kw,
                     float* __restrict__ ws)
{
    const int c    = blockIdx.x >> 1;
    const int half = blockIdx.x & 1;
    const int b    = blockIdx.y;
    const int t    = threadIdx.x;

    // Per-sample kernel index (uniform): jnp.round = RNE = rintf.
    float t60 = t60s[b & 7];
    int kidx = (int)rintf(t60 * 100.0f) - 10;
    kidx = __builtin_amdgcn_readfirstlane(kidx);
    const float4* wp = (const float4*)(kw + (size_t)kidx * (CIN * KSZ)
                                          + (size_t)c * (CPC * KSZ));

    // Thread's q pair: q = qbase + 2t + {0,1}. Clamp loads in-bounds:
    //  float2 at q (q even -> 8B aligned), halo dword at min(q+2, 3999).
    const int qbase = half * QHALF;
    const int tq    = 2 * t;                              // 0..2046
    const int tqc   = tq < QHALF - 2 ? tq : QHALF - 2;    // clamp to 1998
    const int q     = qbase + tqc;
    const int qh    = (q + 2) < NQ ? (q + 2) : NQ;        // <= 3999

    const float* xr = x + ((size_t)b * CIN + (size_t)c * CPC) * L_IN;
    const float* xp = xr + q;
    const float* xq = xr + qh;

    float acc[16];
    #pragma unroll
    for (int j = 0; j < 16; ++j) acc[j] = 0.0f;

    #pragma unroll 4
    for (int ci = 0; ci < CPC; ++ci) {
        float2 a  = *(const float2*)xp;   // block reads 8 KB contiguous/row
        float  an = *xq;                  // halo x[q+2] (L1-hit)
        xp += L_IN;
        xq += L_IN;

        float4 w0 = wp[4 * ci + 0];       // uniform -> s_load_dwordx4
        float4 w1 = wp[4 * ci + 1];
        float4 w2 = wp[4 * ci + 2];
        float4 w3 = wp[4 * ci + 3];
        const float wf[16] = {w0.x, w0.y, w0.z, w0.w, w1.x, w1.y, w1.z, w1.w,
                              w2.x, w2.y, w2.z, w2.w, w3.x, w3.y, w3.z, w3.w};

        const float x0v[2] = {a.x, a.y};
        const float x1v[2] = {a.y, an};
        #pragma unroll
        for (int qi = 0; qi < 2; ++qi)
            #pragma unroll
            for (int r = 0; r < 8; ++r) {
                acc[qi * 8 + r] = fmaf(x1v[qi], wf[r],     acc[qi * 8 + r]);
                acc[qi * 8 + r] = fmaf(x0v[qi], wf[r + 8], acc[qi * 8 + r]);
            }
    }

    // Zero the one invalid output (global q = 3999: half=1, tq=1998, qi=1).
    #pragma unroll
    for (int qi = 0; qi < 2; ++qi)
        if (qbase + tq + qi > NQ - 1)
            #pragma unroll
            for (int r = 0; r < 8; ++r) acc[qi * 8 + r] = 0.0f;

    // Only authentic threads store (clamped tails would race the other half).
    // 16 contiguous floats at j0 = 8*(qbase + tq): halves are disjoint.
    if (tq < QHALF) {
        float* pd = ws + (size_t)b * PBSTR + (size_t)c * PSTR
                       + (size_t)8 * (qbase + tq);
        #pragma unroll
        for (int k = 0; k < 4; ++k)
            ((float4*)pd)[k] = ((const float4*)acc)[k];
    }
}

// ---------------- Phase 2: reduce 8 chunk-partials per sample ---------------
__global__ __launch_bounds__(512)
void dereverb_phase2(const float* __restrict__ ws,
                     float* __restrict__ out)
{
    const int seg = blockIdx.x;          // 16 segments of 2048 outputs
    const int b   = blockIdx.y;
    const int i   = (seg << 11) + 4 * threadIdx.x;
    if (i < LOUT) {                      // LOUT % 4 == 0 -> full float4 valid
        const float* p = ws + (size_t)b * PBSTR + i;
        float4 s = make_float4(0.f, 0.f, 0.f, 0.f);
        #pragma unroll
        for (int c = 0; c < NCH; ++c) {
            float4 v = *(const float4*)(p + c * PSTR);
            s.x += v.x; s.y += v.y; s.z += v.z; s.w += v.w;
        }
        *(float4*)(out + (size_t)b * LOUT + i) = s;
    }
}

extern "C" void kernel_launch(void* const* d_in, const int* in_sizes, int n_in,
                              void* d_out, int out_size, void* d_ws, size_t ws_size,
                              hipStream_t stream) {
    const float* x    = (const float*)d_in[0];   // (16, 512, 4000)
    const float* t60s = (const float*)d_in[1];   // (8,)
    const float* kw   = (const float*)d_in[2];   // (41, 512, 1, 16)
    float* out = (float*)d_out;                  // (16, 1, 31992)
    float* ws  = (float*)d_ws;                   // 16 MB partials

    dim3 g1(NCH * 2, 16);                        // 256 blocks, 1/CU
    dereverb_phase1<<<g1, 1024, 0, stream>>>(x, t60s, kw, ws);
    dim3 g2(16, 16);                             // 256 blocks
    dereverb_phase2<<<g2, 512, 0, stream>>>(ws, out);
}